// Round 6
// baseline (219.044 us; speedup 1.0000x reference)
//
#include <hip/hip_runtime.h>
#include <hip/hip_cooperative_groups.h>

namespace cg = cooperative_groups;

#define QMAX 127.0f

typedef int int4v __attribute__((ext_vector_type(4)));
typedef float float4v __attribute__((ext_vector_type(4)));

__device__ __forceinline__ float amax4(float4 v) {
    return fmaxf(fmaxf(fabsf(v.x), fabsf(v.y)), fmaxf(fabsf(v.z), fabsf(v.w)));
}
__device__ __forceinline__ int qone(float v, float s) {
    float q = fminf(fmaxf(rintf(v / s), -QMAX), QMAX);
    return (int)q;
}
__device__ __forceinline__ int qpack4(float4 v, float s) {
    return (qone(v.x, s) & 255) | ((qone(v.y, s) & 255) << 8) |
           ((qone(v.z, s) & 255) << 16) | ((qone(v.w, s) & 255) << 24);
}

// ---- shared building blocks (1024-thr config: wave wv owns cols [wv*64,+64))
#define LOADB(Bb, kc)                                                        \
    do { _Pragma("unroll") for (int j = 0; j < 4; ++j)                       \
        Bb[j] = *(const int4v*)(bbase + ((size_t)j * KC + (kc)) * 1024);     \
    } while (0)
#define LOADA(Af, kc)                                                        \
    do { _Pragma("unroll") for (int i = 0; i < 4; ++i)                       \
        Af[i] = sAv[i * K + (kc) * 64 + lane];                               \
    } while (0)
#define MF(Bb, Af)                                                           \
    do { _Pragma("unroll") for (int j = 0; j < 4; ++j)                       \
        _Pragma("unroll") for (int i = 0; i < 4; ++i)                        \
            acc[j][i] = __builtin_amdgcn_mfma_i32_16x16x64_i8(               \
                Bb[j], Af[i], acc[j][i], 0, 0, 0);                           \
    } while (0)

// quantize one 16B-group of w into frag-order qw:
//   slot(g,kc,q,r) = (g*KC + kc)*64 + q*16 + r  holds qw[n=g*16+r][k=kc*64+q*16..+16]
__device__ __forceinline__ void quant_w_slice(const float* __restrict__ w,
                                              int4v* __restrict__ qw, int i,
                                              int kshift, int KC, float wsc) {
    const float4* sw = (const float4*)w;
    float4 v0 = sw[4 * i + 0];
    float4 v1 = sw[4 * i + 1];
    float4 v2 = sw[4 * i + 2];
    float4 v3 = sw[4 * i + 3];
    int4v o = { qpack4(v0, wsc), qpack4(v1, wsc),
                qpack4(v2, wsc), qpack4(v3, wsc) };
    const int n = i >> kshift;
    const int kg = i & ((1 << kshift) - 1);
    const int kc = kg >> 2, q = kg & 3;
    const int g = n >> 4, r = n & 15;
    qw[(g * KC + kc) * 64 + q * 16 + r] = o;
}

// fused quantize-stage of A: lane L handles (q=L>>4, r=L&15); reads 64B
// contiguous of row m0+i*16+r, writes slot i*K + kc*64 + L (1KB/wave, conflict-free)
__device__ __forceinline__ void stage_quant_A(const float* __restrict__ x,
                                              char* sA, int m0, int K, int KC,
                                              int lane, int wv, float xs) {
    int4v* sw4 = (int4v*)sA;
    const int kcs = __builtin_ctz(KC);
    const int PPW = KC >> 2;                  // (4*KC pairs) / 16 waves
#pragma unroll 2
    for (int pp = 0; pp < PPW; ++pp) {
        const int pair = wv * PPW + pp;
        const int i = pair >> kcs;            // row-group 0..3
        const int kc = pair & (KC - 1);       // 64B k-chunk
        const int row = m0 + i * 16 + (lane & 15);
        const int k0 = kc * 64 + (lane >> 4) * 16;
        const float4* src = (const float4*)(x + (size_t)row * K + k0);
        float4 v0 = src[0];
        float4 v1 = src[1];
        float4 v2 = src[2];
        float4 v3 = src[3];
        int4v o = { qpack4(v0, xs), qpack4(v1, xs),
                    qpack4(v2, xs), qpack4(v3, xs) };
        sw4[i * K + kc * 64 + lane] = o;
    }
}

// R2's proven barrier-free K-loop + epilogue (register-double-buffered B stream)
__device__ __forceinline__ void kloop_epilogue(const char* sAc,
                                               const char* __restrict__ qb,
                                               const float4* __restrict__ bias4,
                                               float* __restrict__ out,
                                               int N, int K, int KC,
                                               int lane, int wv, int m0, float sc) {
    const int4v* sAv = (const int4v*)sAc;
    const char* bbase = qb + (size_t)(wv * 4) * KC * 1024 + lane * 16;

    int4v acc[4][4];
    const int4v zero = {0, 0, 0, 0};
#pragma unroll
    for (int j = 0; j < 4; ++j)
#pragma unroll
        for (int i = 0; i < 4; ++i) acc[j][i] = zero;

    int4v B0[4], B1[4], Af[4];
    LOADB(B0, 0);
#pragma unroll 1
    for (int kc = 0; kc + 2 < KC; kc += 2) {
        LOADB(B1, kc + 1);      // next slab in flight while computing current
        LOADA(Af, kc);
        MF(B0, Af);
        LOADB(B0, kc + 2);
        LOADA(Af, kc + 1);
        MF(B1, Af);
    }
    LOADB(B1, KC - 1);
    LOADA(Af, KC - 2);
    MF(B0, Af);
    LOADA(Af, KC - 1);
    MF(B1, Af);

    // dequant + bias. Swapped-operand C layout: lane&15 -> row, quad*4+reg -> col.
    const int quad = lane >> 4;
    const int rbase = m0 + (lane & 15);
    const int cb4 = wv * 16;       // float4 column base
#pragma unroll
    for (int j = 0; j < 4; ++j) {
        const float4 bv = bias4[cb4 + j * 4 + quad];
#pragma unroll
        for (int i = 0; i < 4; ++i) {
            const int row = rbase + i * 16;
            float4v v;
            v[0] = (float)acc[j][i][0] * sc + bv.x;
            v[1] = (float)acc[j][i][1] * sc + bv.y;
            v[2] = (float)acc[j][i][2] * sc + bv.z;
            v[3] = (float)acc[j][i][3] * sc + bv.w;
            *((float4v*)(out + (size_t)row * N) + cb4 + j * 4 + quad) = v;
        }
    }
}

// ---------------- R11: single cooperative kernel --------------------------
// Phase1: block b absmaxes its OWN 64-row x strip (leaves it L2-warm for its
// own phase-2 stage) + 1/grid of w; device atomicMax. grid.sync.
// Phase2: quantize 1/grid of w to frag-order qw + quant-stage A to LDS.
// grid.sync (doubles as stage barrier + publishes qw). Phase3: R2 K-loop.
// Deletes 2 kernel launches + their gaps and turns the gemm's 64MB HBM
// x-stream into an L2/L3 re-read.
__global__ __launch_bounds__(1024, 4) void fused_ql_kernel(
        const float* __restrict__ x, const float* __restrict__ w,
        const float4* __restrict__ bias4, float* __restrict__ out,
        int* __restrict__ amax, int4v* __restrict__ qw,
        int M, int N, int K) {
    extern __shared__ char sA[];   // 64 rows x K bytes, frag order (64KB @ K=1024)

    const int KC = K >> 6;
    const int tid = threadIdx.x;
    const int lane = tid & 63;
    const int wv = tid >> 6;       // wave 0..15
    const int bid = blockIdx.x;
    const int m0 = bid * 64;

    // ---- phase 1: absmax (x strip: 16 float4/thread, 4 indep accumulators)
    {
        const float4* xp = (const float4*)(x + (size_t)m0 * K);
        const int n4s = K << 4;                  // 64*K/4
        float a0 = 0.f, a1 = 0.f, a2 = 0.f, a3 = 0.f;
        for (int i = tid; i < n4s; i += 4096) {
            a0 = fmaxf(a0, amax4(xp[i]));
            a1 = fmaxf(a1, amax4(xp[i + 1024]));
            a2 = fmaxf(a2, amax4(xp[i + 2048]));
            a3 = fmaxf(a3, amax4(xp[i + 3072]));
        }
        float ax = fmaxf(fmaxf(a0, a1), fmaxf(a2, a3));
        float aw = 0.f;
        const float4* wp = (const float4*)w;
        const int n4w = (N * K) >> 2;
        const int gs = (int)gridDim.x << 10;
        for (int i = (bid << 10) + tid; i < n4w; i += gs)
            aw = fmaxf(aw, amax4(wp[i]));
        for (int off = 32; off; off >>= 1) {
            ax = fmaxf(ax, __shfl_down(ax, off, 64));
            aw = fmaxf(aw, __shfl_down(aw, off, 64));
        }
        float* red = (float*)sA;               // reuse LDS before staging
        if (lane == 0) { red[wv] = ax; red[16 + wv] = aw; }
        __syncthreads();
        if (tid == 0) {
            float mx = red[0], mw = red[16];
            for (int k2 = 1; k2 < 16; ++k2) {
                mx = fmaxf(mx, red[k2]);
                mw = fmaxf(mw, red[16 + k2]);
            }
            // ws poison 0xAAAAAAAA is negative as int; abs-float bits are
            // non-negative -> atomicMax needs no init.
            atomicMax(amax + 0, (int)__float_as_uint(mx));
            atomicMax(amax + 1, (int)__float_as_uint(mw));
        }
    }
    cg::this_grid().sync();

    const float xs = __uint_as_float((unsigned)__hip_atomic_load(
                         amax + 0, __ATOMIC_RELAXED, __HIP_MEMORY_SCOPE_AGENT)) / QMAX;
    const float wsc = __uint_as_float((unsigned)__hip_atomic_load(
                         amax + 1, __ATOMIC_RELAXED, __HIP_MEMORY_SCOPE_AGENT)) / QMAX;

    // ---- phase 2a: quantize this block's slice of w into frag-order qw
    {
        const int n16w = (N * K) >> 4;
        const int per = n16w / (int)gridDim.x;   // 256 for 1024x1024 w
        const int kshift = __builtin_ctz(K >> 4);
        for (int t = tid; t < per; t += 1024)
            quant_w_slice(w, qw, bid * per + t, kshift, KC, wsc);
    }
    // ---- phase 2b: quant-stage A (x strip is L2/L3-warm from phase 1)
    stage_quant_A(x, sA, m0, K, KC, lane, wv, xs);

    cg::this_grid().sync();   // stage barrier + qw published device-wide

    // ---- phase 3: K-loop + epilogue
    kloop_epilogue(sA, (const char*)qw, bias4, out, N, K, KC, lane, wv, m0,
                   xs * wsc);
}

// ---------------- fallback: R2's proven 3-kernel path ---------------------
__global__ void absmax2_kernel(const float4* __restrict__ px, int n4x,
                               const float4* __restrict__ pw, int n4w,
                               int gx, int* __restrict__ amax) {
    const float4* p; int n4; int* out; int nb, bid;
    if ((int)blockIdx.x < gx) { p = px; n4 = n4x; out = amax + 0; nb = gx; bid = blockIdx.x; }
    else { p = pw; n4 = n4w; out = amax + 1; nb = gridDim.x - gx; bid = blockIdx.x - gx; }
    const int S = nb * blockDim.x;
    int i = bid * blockDim.x + threadIdx.x;
    float a = 0.f, b = 0.f, c = 0.f, d = 0.f;
    for (; i + 3 * S < n4; i += 4 * S) {
        float4 v0 = p[i];
        float4 v1 = p[i + S];
        float4 v2 = p[i + 2 * S];
        float4 v3 = p[i + 3 * S];
        a = fmaxf(a, amax4(v0));
        b = fmaxf(b, amax4(v1));
        c = fmaxf(c, amax4(v2));
        d = fmaxf(d, amax4(v3));
    }
    for (; i < n4; i += S) a = fmaxf(a, amax4(p[i]));
    float m = fmaxf(fmaxf(a, b), fmaxf(c, d));
    for (int off = 32; off; off >>= 1) m = fmaxf(m, __shfl_down(m, off, 64));
    __shared__ float sm[4];
    if ((threadIdx.x & 63) == 0) sm[threadIdx.x >> 6] = m;
    __syncthreads();
    if (threadIdx.x == 0) {
        float bm = fmaxf(fmaxf(sm[0], sm[1]), fmaxf(sm[2], sm[3]));
        atomicMax(out, (int)__float_as_uint(bm));
    }
}

__global__ void quantw_kernel(const float* __restrict__ w, int4v* __restrict__ dw,
                              int n16w, int kshift, int KC,
                              const int* __restrict__ amax) {
    const float scale = __uint_as_float((unsigned)amax[1]) / QMAX;
    const int stride = gridDim.x * blockDim.x;
    for (int i = blockIdx.x * blockDim.x + threadIdx.x; i < n16w; i += stride)
        quant_w_slice(w, dw, i, kshift, KC, scale);
}

__global__ __launch_bounds__(1024, 4) void gemm_fused_kernel(
        const float* __restrict__ x, const char* __restrict__ qb,
        const float4* __restrict__ bias4, const int* __restrict__ amax,
        float* __restrict__ out, int M, int N, int K) {
    extern __shared__ char sA[];
    const int KC = K >> 6;
    const int tid = threadIdx.x;
    const int lane = tid & 63;
    const int wv = tid >> 6;
    const int m0 = blockIdx.x * 64;
    const float xs = __uint_as_float((unsigned)amax[0]) / QMAX;
    const float wsc = __uint_as_float((unsigned)amax[1]) / QMAX;
    stage_quant_A(x, sA, m0, K, KC, lane, wv, xs);
    __syncthreads();
    kloop_epilogue(sA, qb, bias4, out, N, K, KC, lane, wv, m0, xs * wsc);
}

extern "C" void kernel_launch(void* const* d_in, const int* in_sizes, int n_in,
                              void* d_out, int out_size, void* d_ws, size_t ws_size,
                              hipStream_t stream) {
    const float* x = (const float*)d_in[0];     // [M, K]
    const float* w = (const float*)d_in[1];     // [N, K] (row-major = B^T)
    const float* bias = (const float*)d_in[2];  // [N]
    float* out = (float*)d_out;

    const int xn = in_sizes[0];
    const int wn = in_sizes[1];
    const int N = in_sizes[2];
    const int K = wn / N;
    const int M = xn / K;
    const int KC = K >> 6;
    const int kshift = __builtin_ctz(K >> 4);   // 16B-groups per qw row

    int* amax = (int*)d_ws;                     // [0]=absmax(x) bits, [1]=absmax(w) bits
    char* qwb = (char*)d_ws + 1024;             // frag-order packed weights (1MB)
    int4v* qwv = (int4v*)qwb;
    const float4* bias4 = (const float4*)bias;

    const int grid = M / 64;                    // 256 blocks = 1/CU (co-resident)
    void* args[] = { (void*)&x, (void*)&w, (void*)&bias4, (void*)&out,
                     (void*)&amax, (void*)&qwv,
                     (void*)&M, (void*)&N, (void*)&K };
    hipError_t err = hipLaunchCooperativeKernel(
        (const void*)fused_ql_kernel, dim3(grid), dim3(1024), args,
        (unsigned)(64 * K), stream);
    if (err != hipSuccess) {
        // fallback = R2's proven 3-kernel pipeline (161.4us)
        const int GAX = 2048, GAW = 256;
        absmax2_kernel<<<GAX + GAW, 256, 0, stream>>>(
            (const float4*)x, xn / 4, (const float4*)w, wn / 4, GAX, amax);
        quantw_kernel<<<256, 256, 0, stream>>>(
            w, qwv, wn / 16, kshift, KC, amax);
        gemm_fused_kernel<<<M / 64, 1024, 64 * K, stream>>>(
            x, qwb, bias4, amax, out, M, N, K);
    }
}

// Round 7
// 191.182 us; speedup vs baseline: 1.1457x; 1.1457x over previous
//
#include <hip/hip_runtime.h>

#define QMAX 127.0f

typedef int int4v __attribute__((ext_vector_type(4)));
typedef float float4v __attribute__((ext_vector_type(4)));

__device__ __forceinline__ float amax4(float4 v) {
    return fmaxf(fmaxf(fabsf(v.x), fabsf(v.y)), fmaxf(fabsf(v.z), fabsf(v.w)));
}
__device__ __forceinline__ int qone(float v, float s) {
    float q = fminf(fmaxf(rintf(v / s), -QMAX), QMAX);
    return (int)q;
}
__device__ __forceinline__ int qpack4(float4 v, float s) {
    return (qone(v.x, s) & 255) | ((qone(v.y, s) & 255) << 8) |
           ((qone(v.z, s) & 255) << 16) | ((qone(v.w, s) & 255) << 24);
}

// ---------------- absmax for x and w (R1-proven, ~12us) -------------------
// No init needed: ws poison 0xAAAAAAAA is negative as signed int; abs-float
// bit patterns are non-negative ints, so atomicMax(int*) recovers the max.
__global__ void absmax2_kernel(const float4* __restrict__ px, int n4x,
                               const float4* __restrict__ pw, int n4w,
                               int gx, int* __restrict__ amax) {
    const float4* p; int n4; int* out; int nb, bid;
    if ((int)blockIdx.x < gx) { p = px; n4 = n4x; out = amax + 0; nb = gx; bid = blockIdx.x; }
    else { p = pw; n4 = n4w; out = amax + 1; nb = gridDim.x - gx; bid = blockIdx.x - gx; }
    const int S = nb * blockDim.x;
    int i = bid * blockDim.x + threadIdx.x;
    float a = 0.f, b = 0.f, c = 0.f, d = 0.f;
    for (; i + 3 * S < n4; i += 4 * S) {
        float4 v0 = p[i];
        float4 v1 = p[i + S];
        float4 v2 = p[i + 2 * S];
        float4 v3 = p[i + 3 * S];
        a = fmaxf(a, amax4(v0));
        b = fmaxf(b, amax4(v1));
        c = fmaxf(c, amax4(v2));
        d = fmaxf(d, amax4(v3));
    }
    for (; i < n4; i += S) a = fmaxf(a, amax4(p[i]));
    float m = fmaxf(fmaxf(a, b), fmaxf(c, d));
    for (int off = 32; off; off >>= 1) m = fmaxf(m, __shfl_down(m, off, 64));
    __shared__ float sm[4];
    if ((threadIdx.x & 63) == 0) sm[threadIdx.x >> 6] = m;
    __syncthreads();
    if (threadIdx.x == 0) {
        float bm = fmaxf(fmaxf(sm[0], sm[1]), fmaxf(sm[2], sm[3]));
        atomicMax(out, (int)__float_as_uint(bm));
    }
}

// ---------------- quantize W ONLY, repacked to MFMA B-frag order ----------
//   slot(g,kc,q,r) = (g*KC + kc)*64 + q*16 + r  holds qw[n=g*16+r][k=kc*64+q*16..+16]
__global__ void quantw_kernel(const float4* __restrict__ sw, int4v* __restrict__ dw,
                              int n16w, int kshift, int KC,
                              const int* __restrict__ amax) {
    const float scale = __uint_as_float((unsigned)amax[1]) / QMAX;
    const int stride = gridDim.x * blockDim.x;
    for (int i = blockIdx.x * blockDim.x + threadIdx.x; i < n16w; i += stride) {
        float4 v0 = sw[4 * i + 0];
        float4 v1 = sw[4 * i + 1];
        float4 v2 = sw[4 * i + 2];
        float4 v3 = sw[4 * i + 3];
        int4v o = { qpack4(v0, scale), qpack4(v1, scale),
                    qpack4(v2, scale), qpack4(v3, scale) };
        const int n = i >> kshift;
        const int kg = i & ((1 << kshift) - 1);
        const int kc = kg >> 2, q = kg & 3;
        const int g = n >> 4, r = n & 15;
        dw[(g * KC + kc) * 64 + q * 16 + r] = o;
    }
}

// ---------------- int8 GEMM, fused A-quant, K-CHUNKED PIPELINE ------------
// R12: the R2 gemm (41us) ran stage (17us, MFMA idle) -> K-loop -> drain as
// serial phases; inter-block overlap is impossible (1 blk/CU, lockstep
// proven R3/R5/R6). This version overlaps INTRA-block: K is cut into CH =
// KC/4 chunks (256 k-values, 16KB LDS each, ping-pong pair = 32KB). Per
// chunk each wave owns one (i,kcl) pair = 4 float4 x-loads (T14: issue for
// chunk h+1 BEFORE computing chunk h, quantize+ds_write after, one barrier
// per chunk). x HBM latency hides under 64 MFMA/wave; B register double
// buffer streams across chunk boundaries unchanged (chunk len 4 preserves
// B0/B1 parity). Requires KC % 4 == 0 (K=1024 -> KC=16, CH=4).
__global__ __launch_bounds__(1024, 4) void gemm_i8_kernel(
        const float* __restrict__ x, const char* __restrict__ qb,
        const float4* __restrict__ bias4, const int* __restrict__ amax,
        float* __restrict__ out, int M, int N, int K) {
    extern __shared__ char sA[];   // 2 x (64 rows x 256B i8) ping-pong

    const int KC = K >> 6;
    const int CH = KC >> 2;
    const int tid = threadIdx.x;
    const int lane = tid & 63;
    const int wv = tid >> 6;       // wave 0..15, owns cols [wv*64, +64)
    const int m0 = blockIdx.x * 64;

    // this wave's fixed staging assignment: row-group i, chunk-local slab kcl
    const int si = wv >> 2;
    const int skcl = wv & 3;
    const int srow = m0 + si * 16 + (lane & 15);
    const int sk0 = skcl * 64 + (lane >> 4) * 16;  // float offset within chunk
    const float* sbase = x + (size_t)srow * K + sk0;
    const int sslot = si * 256 + skcl * 64 + lane; // int4v slot within buffer

    const float xs = __uint_as_float((unsigned)amax[0]) / QMAX;

    // B frag (g = wv*4 + j, kc): byte offset (g*KC + kc)*1024 + lane*16
    const char* bbase = qb + (size_t)(wv * 4) * KC * 1024 + lane * 16;

#define LOADB(Bb, kc)                                                        \
    do { _Pragma("unroll") for (int j = 0; j < 4; ++j)                       \
        Bb[j] = *(const int4v*)(bbase + ((size_t)j * KC + (kc)) * 1024);     \
    } while (0)
#define LOADA(Af, kcl)                                                       \
    do { _Pragma("unroll") for (int i = 0; i < 4; ++i)                       \
        Af[i] = sAv[i * 256 + (kcl) * 64 + lane];                            \
    } while (0)
#define MF(Bb, Af)                                                           \
    do { _Pragma("unroll") for (int j = 0; j < 4; ++j)                       \
        _Pragma("unroll") for (int i = 0; i < 4; ++i)                        \
            acc[j][i] = __builtin_amdgcn_mfma_i32_16x16x64_i8(               \
                Bb[j], Af[i], acc[j][i], 0, 0, 0);                           \
    } while (0)
#define ISSUEX(h)                                                            \
    do { const float4* sp = (const float4*)(sbase + (h) * 256);              \
        xr0 = sp[0]; xr1 = sp[1]; xr2 = sp[2]; xr3 = sp[3];                  \
    } while (0)
#define QWRITE(h)                                                            \
    do { int4v o = { qpack4(xr0, xs), qpack4(xr1, xs),                       \
                     qpack4(xr2, xs), qpack4(xr3, xs) };                     \
        ((int4v*)(sA + ((h) & 1) * 16384))[sslot] = o;                       \
    } while (0)

    float4 xr0, xr1, xr2, xr3;
    int4v B0[4], B1[4], Af[4];

    // prologue: stage chunk 0; first B slab rides the same vmcnt window
    ISSUEX(0);
    LOADB(B0, 0);
    QWRITE(0);
    __syncthreads();

    int4v acc[4][4];
    const int4v zero = {0, 0, 0, 0};
#pragma unroll
    for (int j = 0; j < 4; ++j)
#pragma unroll
        for (int i = 0; i < 4; ++i) acc[j][i] = zero;

#pragma unroll 1
    for (int h = 0; h < CH; ++h) {
        const int4v* sAv = (const int4v*)(sA + (h & 1) * 16384);
        const int kc0 = h * 4;
        const bool more = (h + 1 < CH);
        if (more) ISSUEX(h + 1);           // x loads in flight under MFMA
        LOADB(B1, kc0 + 1); LOADA(Af, 0); MF(B0, Af);
        LOADB(B0, kc0 + 2); LOADA(Af, 1); MF(B1, Af);
        LOADB(B1, kc0 + 3); LOADA(Af, 2); MF(B0, Af);
        if (more) LOADB(B0, kc0 + 4);      // next chunk's first slab
        LOADA(Af, 3); MF(B1, Af);
        if (more) {
            QWRITE(h + 1);                 // waits x loads (now ~covered)
            __syncthreads();
        }
    }

    // dequant + bias. Swapped-operand C layout: lane&15 -> row, quad*4+reg -> col.
    const float sc = xs * (__uint_as_float((unsigned)amax[1]) / QMAX);
    const int quad = lane >> 4;
    const int rbase = m0 + (lane & 15);
    const int cb4 = wv * 16;       // float4 column base
#pragma unroll
    for (int j = 0; j < 4; ++j) {
        const float4 bv = bias4[cb4 + j * 4 + quad];
#pragma unroll
        for (int i = 0; i < 4; ++i) {
            const int row = rbase + i * 16;
            float4v v;
            v[0] = (float)acc[j][i][0] * sc + bv.x;
            v[1] = (float)acc[j][i][1] * sc + bv.y;
            v[2] = (float)acc[j][i][2] * sc + bv.z;
            v[3] = (float)acc[j][i][3] * sc + bv.w;
            *((float4v*)(out + (size_t)row * N) + cb4 + j * 4 + quad) = v;
        }
    }
}

extern "C" void kernel_launch(void* const* d_in, const int* in_sizes, int n_in,
                              void* d_out, int out_size, void* d_ws, size_t ws_size,
                              hipStream_t stream) {
    const float* x = (const float*)d_in[0];     // [M, K]
    const float* w = (const float*)d_in[1];     // [N, K] (row-major = B^T)
    const float* bias = (const float*)d_in[2];  // [N]
    float* out = (float*)d_out;

    const int xn = in_sizes[0];
    const int wn = in_sizes[1];
    const int N = in_sizes[2];
    const int K = wn / N;
    const int M = xn / K;
    const int KC = K >> 6;
    const int kshift = __builtin_ctz(K >> 4);   // 16B-groups per qw row

    int* amax = (int*)d_ws;                     // [0]=absmax(x) bits, [1]=absmax(w) bits
    char* qw = (char*)d_ws + 1024;              // frag-order packed weights (1MB)

    const int GAX = 2048, GAW = 256;
    absmax2_kernel<<<GAX + GAW, 256, 0, stream>>>(
        (const float4*)x, xn / 4, (const float4*)w, wn / 4, GAX, amax);

    quantw_kernel<<<256, 256, 0, stream>>>(
        (const float4*)w, (int4v*)qw, wn / 16, kshift, KC, amax);

    gemm_i8_kernel<<<M / 64, 1024, 32768, stream>>>(
        x, qw, (const float4*)bias, amax, out, M, N, K);
}

// Round 8
// 190.221 us; speedup vs baseline: 1.1515x; 1.0051x over previous
//
#include <hip/hip_runtime.h>

#define QMAX 127.0f

typedef int int4v __attribute__((ext_vector_type(4)));
typedef float float4v __attribute__((ext_vector_type(4)));

__device__ __forceinline__ float amax4(float4 v) {
    return fmaxf(fmaxf(fabsf(v.x), fabsf(v.y)), fmaxf(fabsf(v.z), fabsf(v.w)));
}
__device__ __forceinline__ int qone(float v, float s) {
    float q = fminf(fmaxf(rintf(v / s), -QMAX), QMAX);
    return (int)q;
}
__device__ __forceinline__ int qpack4(float4 v, float s) {
    return (qone(v.x, s) & 255) | ((qone(v.y, s) & 255) << 8) |
           ((qone(v.z, s) & 255) << 16) | ((qone(v.w, s) & 255) << 24);
}

// ---------------- absmax for x and w (R1-proven, ~12us) -------------------
// No init needed: ws poison 0xAAAAAAAA is negative as signed int; abs-float
// bit patterns are non-negative ints, so atomicMax(int*) recovers the max.
__global__ void absmax2_kernel(const float4* __restrict__ px, int n4x,
                               const float4* __restrict__ pw, int n4w,
                               int gx, int* __restrict__ amax) {
    const float4* p; int n4; int* out; int nb, bid;
    if ((int)blockIdx.x < gx) { p = px; n4 = n4x; out = amax + 0; nb = gx; bid = blockIdx.x; }
    else { p = pw; n4 = n4w; out = amax + 1; nb = gridDim.x - gx; bid = blockIdx.x - gx; }
    const int S = nb * blockDim.x;
    int i = bid * blockDim.x + threadIdx.x;
    float a = 0.f, b = 0.f, c = 0.f, d = 0.f;
    for (; i + 3 * S < n4; i += 4 * S) {
        float4 v0 = p[i];
        float4 v1 = p[i + S];
        float4 v2 = p[i + 2 * S];
        float4 v3 = p[i + 3 * S];
        a = fmaxf(a, amax4(v0));
        b = fmaxf(b, amax4(v1));
        c = fmaxf(c, amax4(v2));
        d = fmaxf(d, amax4(v3));
    }
    for (; i < n4; i += S) a = fmaxf(a, amax4(p[i]));
    float m = fmaxf(fmaxf(a, b), fmaxf(c, d));
    for (int off = 32; off; off >>= 1) m = fmaxf(m, __shfl_down(m, off, 64));
    __shared__ float sm[4];
    if ((threadIdx.x & 63) == 0) sm[threadIdx.x >> 6] = m;
    __syncthreads();
    if (threadIdx.x == 0) {
        float bm = fmaxf(fmaxf(sm[0], sm[1]), fmaxf(sm[2], sm[3]));
        atomicMax(out, (int)__float_as_uint(bm));
    }
}

// ---------------- quantize W ONLY, repacked to MFMA B-frag order ----------
//   slot(g,kc,q,r) = (g*KC + kc)*64 + q*16 + r  holds qw[n=g*16+r][k=kc*64+q*16..+16]
__global__ void quantw_kernel(const float4* __restrict__ sw, int4v* __restrict__ dw,
                              int n16w, int kshift, int KC,
                              const int* __restrict__ amax) {
    const float scale = __uint_as_float((unsigned)amax[1]) / QMAX;
    const int stride = gridDim.x * blockDim.x;
    for (int i = blockIdx.x * blockDim.x + threadIdx.x; i < n16w; i += stride) {
        float4 v0 = sw[4 * i + 0];
        float4 v1 = sw[4 * i + 1];
        float4 v2 = sw[4 * i + 2];
        float4 v3 = sw[4 * i + 3];
        int4v o = { qpack4(v0, scale), qpack4(v1, scale),
                    qpack4(v2, scale), qpack4(v3, scale) };
        const int n = i >> kshift;
        const int kg = i & ((1 << kshift) - 1);
        const int kc = kg >> 2, q = kg & 3;
        const int g = n >> 4, r = n & 15;
        dw[(g * KC + kc) * 64 + q * 16 + r] = o;
    }
}

// ---------------- int8 GEMM, fused A-quant, K-CHUNKED PIPELINE v2 ---------
// R13 = R12 with the SPILL FIXED. R12's counters showed ~80MB scratch writes
// + ~33MB scratch reads: acc(64) + Bdbuf(32) + Af(16) + 4xfloat4 prefetch
// (16) + addr > the hard 128-reg cap of a 1024-thr block. Here: (1) x is
// prefetched in HALF-chunks (2 float4 = 8 regs in flight; half-a packs to 2
// ints while half-b loads; single b128 LDS write), (2) Af halved to 2 frags
// (MFMA in two i-halves), (3) last chunk peeled (no 'more' branches). Peak
// ~126 <= 128. Schedule per chunk h: issue x(h+1) half-a -> 8 MFMA -> pack,
// issue half-b -> 8 MFMA -> pack+ds_write -> barrier. x HBM/L3 latency
// hides under MFMA; B register double buffer unchanged across chunks.
__global__ __launch_bounds__(1024, 4) void gemm_i8_kernel(
        const float* __restrict__ x, const char* __restrict__ qb,
        const float4* __restrict__ bias4, const int* __restrict__ amax,
        float* __restrict__ out, int M, int N, int K) {
    extern __shared__ char sA[];   // 2 x (64 rows x 256B i8) ping-pong

    const int KC = K >> 6;
    const int CH = KC >> 2;        // chunks of 4 kc-slabs (256 k-values)
    const int tid = threadIdx.x;
    const int lane = tid & 63;
    const int wv = tid >> 6;       // wave 0..15, owns cols [wv*64, +64)
    const int m0 = blockIdx.x * 64;

    // staging assignment: wave -> (row-group si, chunk-local slab skcl);
    // lane -> (q=lane>>4, r=lane&15). 64B contiguous read per lane.
    const int si = wv >> 2;
    const int skcl = wv & 3;
    const int srow = m0 + si * 16 + (lane & 15);
    const int sk0 = skcl * 64 + (lane >> 4) * 16;
    const float4* sbase4 = (const float4*)(x + (size_t)srow * K + sk0);
    const int sslot = si * 256 + skcl * 64 + lane; // int4v slot in buffer

    const float xs = __uint_as_float((unsigned)amax[0]) / QMAX;

    // B frag (g = wv*4 + j, kc): byte offset ((wv*4+j)*KC + kc)*1024 + lane*16
    const char* bbase = qb + (size_t)(wv * 4) * KC * 1024 + lane * 16;

#define LOADB(Bb, kc)                                                        \
    do { _Pragma("unroll") for (int j = 0; j < 4; ++j)                       \
        Bb[j] = *(const int4v*)(bbase + ((size_t)j * KC + (kc)) * 1024);     \
    } while (0)
#define LOADA2(kcl, ih)                                                      \
    do { _Pragma("unroll") for (int i = 0; i < 2; ++i)                       \
        Af[i] = sAv[((ih) * 2 + i) * 256 + (kcl) * 64 + lane];               \
    } while (0)
#define MF2(Bb, ih)                                                          \
    do { _Pragma("unroll") for (int j = 0; j < 4; ++j)                       \
        _Pragma("unroll") for (int i = 0; i < 2; ++i)                        \
            acc[j][(ih) * 2 + i] = __builtin_amdgcn_mfma_i32_16x16x64_i8(    \
                Bb[j], Af[i], acc[j][(ih) * 2 + i], 0, 0, 0);                \
    } while (0)
#define KCQUAD(Bb0, Bb1, kcl0, kcl1)                                         \
    do { LOADA2(kcl0, 0); MF2(Bb0, 0); LOADA2(kcl0, 1); MF2(Bb0, 1);         \
         LOADA2(kcl1, 0); MF2(Bb1, 0); LOADA2(kcl1, 1); MF2(Bb1, 1);         \
    } while (0)
#define ISSUEA(h) do { xr0 = sbase4[(h) * 64]; xr1 = sbase4[(h) * 64 + 1]; } while (0)
#define ISSUEB(h) do { xr0 = sbase4[(h) * 64 + 2]; xr1 = sbase4[(h) * 64 + 3]; } while (0)

    float4 xr0, xr1;
    int qa0, qa1;
    int4v B0[4], B1[4], Af[2];

    // prologue: stage chunk 0 (not overlapped); first B slab in same window
    ISSUEA(0);
    LOADB(B0, 0);
    qa0 = qpack4(xr0, xs); qa1 = qpack4(xr1, xs);
    ISSUEB(0);
    {
        int4v o = { qa0, qa1, qpack4(xr0, xs), qpack4(xr1, xs) };
        ((int4v*)sA)[sslot] = o;
    }
    __syncthreads();

    int4v acc[4][4];
    const int4v zero = {0, 0, 0, 0};
#pragma unroll
    for (int j = 0; j < 4; ++j)
#pragma unroll
        for (int i = 0; i < 4; ++i) acc[j][i] = zero;

#pragma unroll 1
    for (int h = 0; h < CH - 1; ++h) {
        const int4v* sAv = (const int4v*)(sA + (h & 1) * 16384);
        const int kc0 = h * 4;
        ISSUEA(h + 1);                         // x half-a in flight under MFMA
        LOADB(B1, kc0 + 1);
        KCQUAD(B0, B1, 0, 1);
        LOADB(B0, kc0 + 2);
        qa0 = qpack4(xr0, xs); qa1 = qpack4(xr1, xs);
        ISSUEB(h + 1);                         // x half-b in flight under MFMA
        LOADB(B1, kc0 + 3);
        KCQUAD(B0, B1, 2, 3);
        LOADB(B0, kc0 + 4);                    // next chunk's first slab
        {
            int4v o = { qa0, qa1, qpack4(xr0, xs), qpack4(xr1, xs) };
            ((int4v*)(sA + ((h + 1) & 1) * 16384))[sslot] = o;
        }
        __syncthreads();
    }
    {   // peeled last chunk: no staging, no next-B prefetch
        const int4v* sAv = (const int4v*)(sA + ((CH - 1) & 1) * 16384);
        const int kc0 = (CH - 1) * 4;
        LOADB(B1, kc0 + 1);
        KCQUAD(B0, B1, 0, 1);
        LOADB(B0, kc0 + 2);
        LOADB(B1, kc0 + 3);
        KCQUAD(B0, B1, 2, 3);
    }

    // dequant + bias. Swapped-operand C layout: lane&15 -> row, quad*4+reg -> col.
    const float sc = xs * (__uint_as_float((unsigned)amax[1]) / QMAX);
    const int quad = lane >> 4;
    const int rbase = m0 + (lane & 15);
    const int cb4 = wv * 16;       // float4 column base
#pragma unroll
    for (int j = 0; j < 4; ++j) {
        const float4 bv = bias4[cb4 + j * 4 + quad];
#pragma unroll
        for (int i = 0; i < 4; ++i) {
            const int row = rbase + i * 16;
            float4v v;
            v[0] = (float)acc[j][i][0] * sc + bv.x;
            v[1] = (float)acc[j][i][1] * sc + bv.y;
            v[2] = (float)acc[j][i][2] * sc + bv.z;
            v[3] = (float)acc[j][i][3] * sc + bv.w;
            *((float4v*)(out + (size_t)row * N) + cb4 + j * 4 + quad) = v;
        }
    }
}

extern "C" void kernel_launch(void* const* d_in, const int* in_sizes, int n_in,
                              void* d_out, int out_size, void* d_ws, size_t ws_size,
                              hipStream_t stream) {
    const float* x = (const float*)d_in[0];     // [M, K]
    const float* w = (const float*)d_in[1];     // [N, K] (row-major = B^T)
    const float* bias = (const float*)d_in[2];  // [N]
    float* out = (float*)d_out;

    const int xn = in_sizes[0];
    const int wn = in_sizes[1];
    const int N = in_sizes[2];
    const int K = wn / N;
    const int M = xn / K;
    const int KC = K >> 6;
    const int kshift = __builtin_ctz(K >> 4);   // 16B-groups per qw row

    int* amax = (int*)d_ws;                     // [0]=absmax(x) bits, [1]=absmax(w) bits
    char* qw = (char*)d_ws + 1024;              // frag-order packed weights (1MB)

    const int GAX = 2048, GAW = 256;
    absmax2_kernel<<<GAX + GAW, 256, 0, stream>>>(
        (const float4*)x, xn / 4, (const float4*)w, wn / 4, GAX, amax);

    quantw_kernel<<<256, 256, 0, stream>>>(
        (const float4*)w, (int4v*)qw, wn / 16, kshift, KC, amax);

    gemm_i8_kernel<<<M / 64, 1024, 32768, stream>>>(
        x, qw, (const float4*)bias, amax, out, M, N, K);
}

// Round 9
// 178.542 us; speedup vs baseline: 1.2268x; 1.0654x over previous
//
#include <hip/hip_runtime.h>

#define QMAX 127.0f

typedef int int4v __attribute__((ext_vector_type(4)));
typedef float float4v __attribute__((ext_vector_type(4)));

__device__ __forceinline__ float amax4(float4 v) {
    return fmaxf(fmaxf(fabsf(v.x), fabsf(v.y)), fmaxf(fabsf(v.z), fabsf(v.w)));
}
__device__ __forceinline__ int qone(float v, float s) {
    float q = fminf(fmaxf(rintf(v / s), -QMAX), QMAX);
    return (int)q;
}
__device__ __forceinline__ int qpack4(float4 v, float s) {
    return (qone(v.x, s) & 255) | ((qone(v.y, s) & 255) << 8) |
           ((qone(v.z, s) & 255) << 16) | ((qone(v.w, s) & 255) << 24);
}

// ---------------- absmax for x and w (R1-proven, ~12us) -------------------
// No init needed: ws poison 0xAAAAAAAA is negative as signed int; abs-float
// bit patterns are non-negative ints, so atomicMax(int*) recovers the max.
__global__ void absmax2_kernel(const float4* __restrict__ px, int n4x,
                               const float4* __restrict__ pw, int n4w,
                               int gx, int* __restrict__ amax) {
    const float4* p; int n4; int* out; int nb, bid;
    if ((int)blockIdx.x < gx) { p = px; n4 = n4x; out = amax + 0; nb = gx; bid = blockIdx.x; }
    else { p = pw; n4 = n4w; out = amax + 1; nb = gridDim.x - gx; bid = blockIdx.x - gx; }
    const int S = nb * blockDim.x;
    int i = bid * blockDim.x + threadIdx.x;
    float a = 0.f, b = 0.f, c = 0.f, d = 0.f;
    for (; i + 3 * S < n4; i += 4 * S) {
        float4 v0 = p[i];
        float4 v1 = p[i + S];
        float4 v2 = p[i + 2 * S];
        float4 v3 = p[i + 3 * S];
        a = fmaxf(a, amax4(v0));
        b = fmaxf(b, amax4(v1));
        c = fmaxf(c, amax4(v2));
        d = fmaxf(d, amax4(v3));
    }
    for (; i < n4; i += S) a = fmaxf(a, amax4(p[i]));
    float m = fmaxf(fmaxf(a, b), fmaxf(c, d));
    for (int off = 32; off; off >>= 1) m = fmaxf(m, __shfl_down(m, off, 64));
    __shared__ float sm[4];
    if ((threadIdx.x & 63) == 0) sm[threadIdx.x >> 6] = m;
    __syncthreads();
    if (threadIdx.x == 0) {
        float bm = fmaxf(fmaxf(sm[0], sm[1]), fmaxf(sm[2], sm[3]));
        atomicMax(out, (int)__float_as_uint(bm));
    }
}

// ---------------- quantize W ONLY, repacked to MFMA B-frag order ----------
//   slot(g,kc,q,r) = (g*KC + kc)*64 + q*16 + r  holds qw[n=g*16+r][k=kc*64+q*16..+16]
__global__ void quantw_kernel(const float4* __restrict__ sw, int4v* __restrict__ dw,
                              int n16w, int kshift, int KC,
                              const int* __restrict__ amax) {
    const float scale = __uint_as_float((unsigned)amax[1]) / QMAX;
    const int stride = gridDim.x * blockDim.x;
    for (int i = blockIdx.x * blockDim.x + threadIdx.x; i < n16w; i += stride) {
        float4 v0 = sw[4 * i + 0];
        float4 v1 = sw[4 * i + 1];
        float4 v2 = sw[4 * i + 2];
        float4 v3 = sw[4 * i + 3];
        int4v o = { qpack4(v0, scale), qpack4(v1, scale),
                    qpack4(v2, scale), qpack4(v3, scale) };
        const int n = i >> kshift;
        const int kg = i & ((1 << kshift) - 1);
        const int kc = kg >> 2, q = kg & 3;
        const int g = n >> 4, r = n & 15;
        dw[(g * KC + kc) * 64 + q * 16 + r] = o;
    }
}

// ---------------- int8 GEMM, fused A-quant, K-CHUNKED PIPELINE v3 ---------
// R14: the R12/R13 pipeline was correct but ran in the WRONG thread
// geometry: a 1024-thr block hard-caps at 128 regs/wave (16 waves @ 4/SIMD)
// and the chunk state (acc64+Bdbuf32+stage) cannot fit -> compiler spilled
// ~40MB/dispatch both rounds. This version: 512 threads -> 256-reg budget.
// 8 waves, 64-row tile, wave owns 128 cols (R0-proven acc[8][4]+epilogue).
// Ledger: acc 128 (AGPR) + Bdbuf 64 + Af 16 + xpref 8 + qa 2 + addr ~20
// = ~238 < 256. Chunk = 2 kc slabs (128 k): each thread stages exactly 4
// float4 of x (issued 2+2 under MFMA, T14), i8 ping-pong LDS 2x8KB, ONE
// barrier per chunk. B traffic identical to R2 (full-N block). Per chunk:
// stage 32KB/CU ~1.3us (HBM) || compute ~1.0us -> x-bound; est ~25us total.
__global__ __launch_bounds__(512, 2) void gemm_i8_kernel(
        const float* __restrict__ x, const char* __restrict__ qb,
        const float4* __restrict__ bias4, const int* __restrict__ amax,
        float* __restrict__ out, int M, int N, int K) {
    extern __shared__ char sA[];   // 2 x (64 rows x 128B i8) ping-pong

    const int KC = K >> 6;
    const int NCH = KC >> 1;       // chunks of 2 kc-slabs (128 k-values)
    const int tid = threadIdx.x;
    const int lane = tid & 63;
    const int wv = tid >> 6;       // wave 0..7, owns cols [wv*128, +128)
    const int m0 = blockIdx.x * 64;

    // staging: wave -> (row-group si = wv>>1, chunk-local slab skcl = wv&1);
    // lane -> (q = lane>>4, r = lane&15); 64B contiguous f32 per lane/chunk.
    const int si = wv >> 1;
    const int skcl = wv & 1;
    const int srow = m0 + si * 16 + (lane & 15);
    const int sk0 = skcl * 64 + (lane >> 4) * 16;
    const float4* sbase4 = (const float4*)(x + (size_t)srow * K + sk0);
    const int sslot = si * 128 + skcl * 64 + lane;   // int4v slot in buffer

    const float xs = __uint_as_float((unsigned)amax[0]) / QMAX;

    // B frag (g = wv*8 + j, kc): byte offset ((wv*8+j)*KC + kc)*1024 + lane*16
    const char* bbase = qb + (size_t)(wv * 8) * KC * 1024 + lane * 16;

#define LOADB(Bb, kc)                                                        \
    do { _Pragma("unroll") for (int j = 0; j < 8; ++j)                       \
        Bb[j] = *(const int4v*)(bbase + ((size_t)j * KC + (kc)) * 1024);     \
    } while (0)
#define LOADA(Af, buf, kcl)                                                  \
    do { const int4v* sAv = (const int4v*)(sA + (buf) * 8192);               \
        _Pragma("unroll") for (int i = 0; i < 4; ++i)                        \
            Af[i] = sAv[i * 128 + (kcl) * 64 + lane];                        \
    } while (0)
#define MF(Bb, Af)                                                           \
    do { _Pragma("unroll") for (int j = 0; j < 8; ++j)                       \
        _Pragma("unroll") for (int i = 0; i < 4; ++i)                        \
            acc[j][i] = __builtin_amdgcn_mfma_i32_16x16x64_i8(               \
                Bb[j], Af[i], acc[j][i], 0, 0, 0);                           \
    } while (0)
#define ISSUEA(h) do { xr0 = sbase4[(h) * 32]; xr1 = sbase4[(h) * 32 + 1]; } while (0)
#define ISSUEB(h) do { xr0 = sbase4[(h) * 32 + 2]; xr1 = sbase4[(h) * 32 + 3]; } while (0)

    float4 xr0, xr1;
    int qa0, qa1;
    int4v B0[8], B1[8], Af[4];

    // prologue: stage chunk 0 (not overlapped); first B slab in same window
    ISSUEA(0);
    LOADB(B0, 0);
    qa0 = qpack4(xr0, xs); qa1 = qpack4(xr1, xs);
    ISSUEB(0);
    {
        int4v o = { qa0, qa1, qpack4(xr0, xs), qpack4(xr1, xs) };
        ((int4v*)sA)[sslot] = o;
    }
    __syncthreads();

    int4v acc[8][4];
    const int4v zero = {0, 0, 0, 0};
#pragma unroll
    for (int j = 0; j < 8; ++j)
#pragma unroll
        for (int i = 0; i < 4; ++i) acc[j][i] = zero;

#pragma unroll 1
    for (int h = 0; h < NCH - 1; ++h) {
        const int kc0 = h * 2;
        ISSUEA(h + 1);                     // x half-a in flight under MFMA
        LOADB(B1, kc0 + 1);
        LOADA(Af, h & 1, 0);
        MF(B0, Af);
        qa0 = qpack4(xr0, xs); qa1 = qpack4(xr1, xs);
        ISSUEB(h + 1);                     // x half-b in flight under MFMA
        LOADB(B0, kc0 + 2);                // next chunk's first slab
        LOADA(Af, h & 1, 1);
        MF(B1, Af);
        {
            int4v o = { qa0, qa1, qpack4(xr0, xs), qpack4(xr1, xs) };
            ((int4v*)(sA + ((h + 1) & 1) * 8192))[sslot] = o;
        }
        __syncthreads();                   // Q[h+1] published for next chunk
    }
    {   // peeled last chunk: no staging, no next-B prefetch
        const int kc0 = (NCH - 1) * 2;
        LOADB(B1, kc0 + 1);
        LOADA(Af, (NCH - 1) & 1, 0);
        MF(B0, Af);
        LOADA(Af, (NCH - 1) & 1, 1);
        MF(B1, Af);
    }

    // dequant + bias. Swapped-operand C layout: lane&15 -> row, quad*4+reg -> col.
    const float sc = xs * (__uint_as_float((unsigned)amax[1]) / QMAX);
    const int quad = lane >> 4;
    const int rbase = m0 + (lane & 15);
    const int cb4 = wv * 32;       // float4 column base
#pragma unroll
    for (int j = 0; j < 8; ++j) {
        const float4 bv = bias4[cb4 + j * 4 + quad];
#pragma unroll
        for (int i = 0; i < 4; ++i) {
            const int row = rbase + i * 16;
            float4v v;
            v[0] = (float)acc[j][i][0] * sc + bv.x;
            v[1] = (float)acc[j][i][1] * sc + bv.y;
            v[2] = (float)acc[j][i][2] * sc + bv.z;
            v[3] = (float)acc[j][i][3] * sc + bv.w;
            *((float4v*)(out + (size_t)row * N) + cb4 + j * 4 + quad) = v;
        }
    }
}

extern "C" void kernel_launch(void* const* d_in, const int* in_sizes, int n_in,
                              void* d_out, int out_size, void* d_ws, size_t ws_size,
                              hipStream_t stream) {
    const float* x = (const float*)d_in[0];     // [M, K]
    const float* w = (const float*)d_in[1];     // [N, K] (row-major = B^T)
    const float* bias = (const float*)d_in[2];  // [N]
    float* out = (float*)d_out;

    const int xn = in_sizes[0];
    const int wn = in_sizes[1];
    const int N = in_sizes[2];
    const int K = wn / N;
    const int M = xn / K;
    const int KC = K >> 6;
    const int kshift = __builtin_ctz(K >> 4);   // 16B-groups per qw row

    int* amax = (int*)d_ws;                     // [0]=absmax(x) bits, [1]=absmax(w) bits
    char* qw = (char*)d_ws + 1024;              // frag-order packed weights (1MB)

    const int GAX = 2048, GAW = 256;
    absmax2_kernel<<<GAX + GAW, 256, 0, stream>>>(
        (const float4*)x, xn / 4, (const float4*)w, wn / 4, GAX, amax);

    quantw_kernel<<<256, 256, 0, stream>>>(
        (const float4*)w, (int4v*)qw, wn / 16, kshift, KC, amax);

    gemm_i8_kernel<<<M / 64, 512, 16384, stream>>>(
        x, qw, (const float4*)bias, amax, out, M, N, K);
}

// Round 10
// 170.130 us; speedup vs baseline: 1.2875x; 1.0494x over previous
//
#include <hip/hip_runtime.h>

#define QMAX 127.0f

typedef int int4v __attribute__((ext_vector_type(4)));
typedef float float4v __attribute__((ext_vector_type(4)));

__device__ __forceinline__ float amax4(float4 v) {
    return fmaxf(fmaxf(fabsf(v.x), fabsf(v.y)), fmaxf(fabsf(v.z), fabsf(v.w)));
}
__device__ __forceinline__ int qone(float v, float s) {
    float q = fminf(fmaxf(rintf(v / s), -QMAX), QMAX);
    return (int)q;
}
__device__ __forceinline__ int qpack4(float4 v, float s) {
    return (qone(v.x, s) & 255) | ((qone(v.y, s) & 255) << 8) |
           ((qone(v.z, s) & 255) << 16) | ((qone(v.w, s) & 255) << 24);
}

// ---------------- absmax for x and w (R1-proven, ~12us) -------------------
// No init needed: ws poison 0xAAAAAAAA is negative as signed int; abs-float
// bit patterns are non-negative ints, so atomicMax(int*) recovers the max.
__global__ void absmax2_kernel(const float4* __restrict__ px, int n4x,
                               const float4* __restrict__ pw, int n4w,
                               int gx, int* __restrict__ amax) {
    const float4* p; int n4; int* out; int nb, bid;
    if ((int)blockIdx.x < gx) { p = px; n4 = n4x; out = amax + 0; nb = gx; bid = blockIdx.x; }
    else { p = pw; n4 = n4w; out = amax + 1; nb = gridDim.x - gx; bid = blockIdx.x - gx; }
    const int S = nb * blockDim.x;
    int i = bid * blockDim.x + threadIdx.x;
    float a = 0.f, b = 0.f, c = 0.f, d = 0.f;
    for (; i + 3 * S < n4; i += 4 * S) {
        float4 v0 = p[i];
        float4 v1 = p[i + S];
        float4 v2 = p[i + 2 * S];
        float4 v3 = p[i + 3 * S];
        a = fmaxf(a, amax4(v0));
        b = fmaxf(b, amax4(v1));
        c = fmaxf(c, amax4(v2));
        d = fmaxf(d, amax4(v3));
    }
    for (; i < n4; i += S) a = fmaxf(a, amax4(p[i]));
    float m = fmaxf(fmaxf(a, b), fmaxf(c, d));
    for (int off = 32; off; off >>= 1) m = fmaxf(m, __shfl_down(m, off, 64));
    __shared__ float sm[4];
    if ((threadIdx.x & 63) == 0) sm[threadIdx.x >> 6] = m;
    __syncthreads();
    if (threadIdx.x == 0) {
        float bm = fmaxf(fmaxf(sm[0], sm[1]), fmaxf(sm[2], sm[3]));
        atomicMax(out, (int)__float_as_uint(bm));
    }
}

// ---------------- quantize W ONLY, repacked to MFMA B-frag order ----------
//   slot(g,kc,q,r) = (g*KC + kc)*64 + q*16 + r  holds qw[n=g*16+r][k=kc*64+q*16..+16]
__global__ void quantw_kernel(const float4* __restrict__ sw, int4v* __restrict__ dw,
                              int n16w, int kshift, int KC,
                              const int* __restrict__ amax) {
    const float scale = __uint_as_float((unsigned)amax[1]) / QMAX;
    const int stride = gridDim.x * blockDim.x;
    for (int i = blockIdx.x * blockDim.x + threadIdx.x; i < n16w; i += stride) {
        float4 v0 = sw[4 * i + 0];
        float4 v1 = sw[4 * i + 1];
        float4 v2 = sw[4 * i + 2];
        float4 v3 = sw[4 * i + 3];
        int4v o = { qpack4(v0, scale), qpack4(v1, scale),
                    qpack4(v2, scale), qpack4(v3, scale) };
        const int n = i >> kshift;
        const int kg = i & ((1 << kshift) - 1);
        const int kc = kg >> 2, q = kg & 3;
        const int g = n >> 4, r = n & 15;
        dw[(g * KC + kc) * 64 + q * 16 + r] = o;
    }
}

// ---------------- int8 GEMM, fused A-quant, K-CHUNKED PIPELINE v4 ---------
// R15: R12/R13/R14 all spilled (~40MB scratch each) because ANY register
// held across the staging vmcnt window competes with acc(128 AGPR) +
// B-dbuf(64) against the 128-arch-VGPR cap (2 waves/SIMD budget is 256
// TOTAL regs incl accumulator). Fix: stage x via global_load_lds -> ZERO
// staging VGPRs. Per chunk (128 k): gll the raw f32 32KB chunk into an LDS
// f32 buffer (linear dest, XOR-swizzled GLOBAL source per G21) while MFMA
// works the current i8 chunk; after the barrier each thread reads 16 f32
// from LDS (same XOR on read; 2-way banks = free), quantizes, writes its
// 16B frag slot in the i8 ping-pong buffer; second barrier; repeat.
// Ledger: acc 128 AGPR + B0/B1 64 + Af 16 + addr ~25, quant temps live only
// while B1/Af dead -> peak ~110 arch VGPR < 128. LDS 32K f32 + 2x8K i8.
__global__ __launch_bounds__(512, 2) void gemm_i8_kernel(
        const float* __restrict__ x, const char* __restrict__ qb,
        const float4* __restrict__ bias4, const int* __restrict__ amax,
        float* __restrict__ out, int M, int N, int K) {
    extern __shared__ char sA[];   // [0,32768): f32 chunk; [32768,49152): i8 ping-pong

    const int KC = K >> 6;
    const int NCH = KC >> 1;       // chunks of 2 kc-slabs (128 k-values)
    const int tid = threadIdx.x;
    const int lane = tid & 63;
    const int wv = tid >> 6;       // wave 0..7, owns cols [wv*128, +128)
    const int m0 = blockIdx.x * 64;

    const float xs = __uint_as_float((unsigned)amax[0]) / QMAX;

    // quant-phase mapping: i8 slot = tid = i_*128 + kcl_*64 + (q_*16 + r_)
    const int r_ = lane & 15, q_ = lane >> 4;
    const int i_ = tid >> 7, kcl_ = (tid >> 6) & 1;
    const int qrow = i_ * 16 + r_;
    const int cb = kcl_ * 16 + q_ * 4;     // first 16B chunk of this thread
    const int rx = qrow & 7;               // XOR swizzle key for this row

    // B frag (g = wv*8 + j, kc): byte offset ((wv*8+j)*KC + kc)*1024 + lane*16
    const char* bbase = qb + (size_t)(wv * 8) * KC * 1024 + lane * 16;

#define LOADB(Bb, kc)                                                        \
    do { _Pragma("unroll") for (int j = 0; j < 8; ++j)                       \
        Bb[j] = *(const int4v*)(bbase + ((size_t)j * KC + (kc)) * 1024);     \
    } while (0)
#define LOADA(Af, buf, kcl)                                                  \
    do { const int4v* sAv = (const int4v*)(sA + 32768 + (buf) * 8192);       \
        _Pragma("unroll") for (int i = 0; i < 4; ++i)                        \
            Af[i] = sAv[i * 128 + (kcl) * 64 + lane];                        \
    } while (0)
#define MF(Bb, Af)                                                           \
    do { _Pragma("unroll") for (int j = 0; j < 8; ++j)                       \
        _Pragma("unroll") for (int i = 0; i < 4; ++i)                        \
            acc[j][i] = __builtin_amdgcn_mfma_i32_16x16x64_i8(               \
                Bb[j], Af[i], acc[j][i], 0, 0, 0);                           \
    } while (0)
// stage chunk h: wave wv covers tile rows [wv*8, wv*8+8), 4 issues x 2 rows.
// LDS dest linear (row*512 + lane*16); global source chunk pre-swizzled
// c^=row&7 so the quant-phase column read is bank-spread (G21 both-sides).
#define GSTAGE(h)                                                            \
    do { _Pragma("unroll") for (int t = 0; t < 4; ++t) {                     \
        const int R0 = wv * 8 + t * 2;                                       \
        const int row = R0 + (lane >> 5);                                    \
        const int cs = (lane & 31) ^ (row & 7);                              \
        const char* src = (const char*)(x + (size_t)(m0 + row) * K           \
                              + (h) * 128 + cs * 4);                         \
        gload16(src, sA + (size_t)R0 * 512 + lane * 16);                     \
    } } while (0)
// quantize staged chunk into i8 buffer `pb` (0/1)
#define QUANT(pb)                                                            \
    do { const float4* f4 = (const float4*)sA;                               \
        float4 v0 = f4[qrow * 32 + ((cb + 0) ^ rx)];                         \
        float4 v1 = f4[qrow * 32 + ((cb + 1) ^ rx)];                         \
        float4 v2 = f4[qrow * 32 + ((cb + 2) ^ rx)];                         \
        float4 v3 = f4[qrow * 32 + ((cb + 3) ^ rx)];                         \
        int4v o = { qpack4(v0, xs), qpack4(v1, xs),                          \
                    qpack4(v2, xs), qpack4(v3, xs) };                        \
        ((int4v*)(sA + 32768 + (pb) * 8192))[tid] = o;                       \
    } while (0)

    typedef const __attribute__((address_space(1))) char glob_char;
    typedef __attribute__((address_space(3))) char lds_char;
#define gload16(g, l) __builtin_amdgcn_global_load_lds((glob_char*)(g), (lds_char*)(l), 16, 0, 0)

    int4v B0[8], B1[8], Af[4];

    // prologue: stage + quantize chunk 0 (not overlapped)
    LOADB(B0, 0);
    GSTAGE(0);
    __syncthreads();               // gll(0) landed (barrier drains vmcnt)
    QUANT(0);
    __syncthreads();               // i8[0] ready

    int4v acc[8][4];
    const int4v zero = {0, 0, 0, 0};
#pragma unroll
    for (int j = 0; j < 8; ++j)
#pragma unroll
        for (int i = 0; i < 4; ++i) acc[j][i] = zero;

#pragma unroll 1
    for (int h = 0; h < NCH - 1; ++h) {
        const int kc0 = h * 2;
        LOADB(B1, kc0 + 1);
        GSTAGE(h + 1);                 // f32 chunk h+1 in flight under MFMA
        LOADA(Af, h & 1, 0);
        MF(B0, Af);
        LOADB(B0, kc0 + 2);            // next chunk's first B slab
        LOADA(Af, h & 1, 1);
        MF(B1, Af);
        __syncthreads();               // gll(h+1) landed; i8[h&1] fully read
        QUANT((h + 1) & 1);
        __syncthreads();               // i8[(h+1)&1] ready
    }
    {   // peeled last chunk: no staging, no next-B prefetch
        const int kc0 = (NCH - 1) * 2;
        LOADB(B1, kc0 + 1);
        LOADA(Af, (NCH - 1) & 1, 0);
        MF(B0, Af);
        LOADA(Af, (NCH - 1) & 1, 1);
        MF(B1, Af);
    }

    // dequant + bias. Swapped-operand C layout: lane&15 -> row, quad*4+reg -> col.
    const float sc = xs * (__uint_as_float((unsigned)amax[1]) / QMAX);
    const int quad = lane >> 4;
    const int rbase = m0 + (lane & 15);
    const int cb4 = wv * 32;       // float4 column base
#pragma unroll
    for (int j = 0; j < 8; ++j) {
        const float4 bv = bias4[cb4 + j * 4 + quad];
#pragma unroll
        for (int i = 0; i < 4; ++i) {
            const int row = rbase + i * 16;
            float4v v;
            v[0] = (float)acc[j][i][0] * sc + bv.x;
            v[1] = (float)acc[j][i][1] * sc + bv.y;
            v[2] = (float)acc[j][i][2] * sc + bv.z;
            v[3] = (float)acc[j][i][3] * sc + bv.w;
            *((float4v*)(out + (size_t)row * N) + cb4 + j * 4 + quad) = v;
        }
    }
}

extern "C" void kernel_launch(void* const* d_in, const int* in_sizes, int n_in,
                              void* d_out, int out_size, void* d_ws, size_t ws_size,
                              hipStream_t stream) {
    const float* x = (const float*)d_in[0];     // [M, K]
    const float* w = (const float*)d_in[1];     // [N, K] (row-major = B^T)
    const float* bias = (const float*)d_in[2];  // [N]
    float* out = (float*)d_out;

    const int xn = in_sizes[0];
    const int wn = in_sizes[1];
    const int N = in_sizes[2];
    const int K = wn / N;
    const int M = xn / K;
    const int KC = K >> 6;
    const int kshift = __builtin_ctz(K >> 4);   // 16B-groups per qw row

    int* amax = (int*)d_ws;                     // [0]=absmax(x) bits, [1]=absmax(w) bits
    char* qw = (char*)d_ws + 1024;              // frag-order packed weights (1MB)

    const int GAX = 2048, GAW = 256;
    absmax2_kernel<<<GAX + GAW, 256, 0, stream>>>(
        (const float4*)x, xn / 4, (const float4*)w, wn / 4, GAX, amax);

    quantw_kernel<<<256, 256, 0, stream>>>(
        (const float4*)w, (int4v*)qw, wn / 16, kshift, KC, amax);

    gemm_i8_kernel<<<M / 64, 512, 49152, stream>>>(
        x, qw, (const float4*)bias, amax, out, M, N, K);
}